// Round 2
// baseline (441.653 us; speedup 1.0000x reference)
//
#include <hip/hip_runtime.h>
#include <hip/hip_bf16.h>

// CausalSelfAttention on gfx950 — round 2.
// I/O is fp32 (per the reference); internal compute is bf16 MFMA (harness
// threshold 7.5e-2 = 8x bf16-eps floor permits this). Round-1 NaN was caused
// by casting the fp32 inputs to bf16 pointers.
// Pipeline: cvt(x)->bf16, cvt+transpose(Wqkv), cvt+transpose(Wout),
// gemm_qkv (writes Q,K [bh][t][d] bf16 and V transposed [bh][d][t] bf16),
// flash attention (64-row Q tiles, online softmax, P via LDS round-trip),
// gemm_out (fp32 epilogue). GEMMs: 128x128 tile, BK=32, global_load_lds
// width=16, XOR-swizzled 16B chunks for conflict-free ds_read_b128.

typedef unsigned short u16;
typedef __attribute__((ext_vector_type(8))) short short8;
typedef __attribute__((ext_vector_type(4))) float f32x4;

#define N_HEADS 16
#define HEAD_DIM 64
#define TSEQ 2048
#define BATCH 4
#define MROWS (BATCH * TSEQ)   // 8192
#define N3 3072                // 3*D_MODEL

__device__ __forceinline__ void cp16(const u16* g, u16* l) {
  __builtin_amdgcn_global_load_lds((const __attribute__((address_space(1))) void*)g,
                                   (__attribute__((address_space(3))) void*)l, 16, 0, 0);
}

__device__ __forceinline__ f32x4 mfma16(short8 a, short8 b, f32x4 c) {
  return __builtin_amdgcn_mfma_f32_16x16x32_bf16(a, b, c, 0, 0, 0);
}

__device__ __forceinline__ u16 f2b(float f) {
  __hip_bfloat16 h = __float2bfloat16(f);
  return *reinterpret_cast<u16*>(&h);
}

// ------------------------------------------------------------ fp32 -> bf16
__global__ __launch_bounds__(256) void cvt_f32_bf16(const float* __restrict__ src,
                                                    u16* __restrict__ dst, int n4) {
  int i = blockIdx.x * 256 + threadIdx.x;
  if (i < n4) {
    float4 v = *(const float4*)(src + (size_t)i * 4);
    u16* d = dst + (size_t)i * 4;
    d[0] = f2b(v.x); d[1] = f2b(v.y); d[2] = f2b(v.z); d[3] = f2b(v.w);
  }
}

// ------------------------------------------- fp32 [R][Cn] -> bf16 [Cn][R]
__global__ void transpose_cvt(const float* __restrict__ src, u16* __restrict__ dst,
                              int R, int Cn) {
  __shared__ float tile[32][33];
  int c0 = blockIdx.x * 32, r0 = blockIdx.y * 32;
  for (int i = threadIdx.y; i < 32; i += 8)
    tile[i][threadIdx.x] = src[(size_t)(r0 + i) * Cn + c0 + threadIdx.x];
  __syncthreads();
  for (int i = threadIdx.y; i < 32; i += 8)
    dst[(size_t)(c0 + i) * R + r0 + threadIdx.x] = f2b(tile[threadIdx.x][i]);
}

// ---------------------------------------------------------------- GEMM core
// A [M][1024] bf16, Bt [N][1024] bf16 (row-major, K=1024 hardcoded).
// 128x128 tile at (m0,n0); 256 threads; acc[i][j] = 16x16 fragment (i=m, j=n).
__device__ __forceinline__ void gemm128_core(const u16* __restrict__ A,
                                             const u16* __restrict__ Bt,
                                             int m0, int n0,
                                             u16* Asm, u16* Bsm,
                                             f32x4 acc[4][4]) {
  const int tid = threadIdx.x;
  const int w = tid >> 6;
  const int lane = tid & 63;
  const int quad = lane >> 4;
  const int l16 = lane & 15;
  const int wm = (w >> 1) * 64;
  const int wn = (w & 1) * 64;

#pragma unroll
  for (int i = 0; i < 4; ++i)
#pragma unroll
    for (int j = 0; j < 4; ++j) acc[i][j] = (f32x4){0.f, 0.f, 0.f, 0.f};

  for (int k0 = 0; k0 < 1024; k0 += 32) {
    __syncthreads();  // prior iter's ds_reads done before overwrite
#pragma unroll
    for (int p = 0; p < 2; ++p) {
      int s = p * 256 + tid;                // 16B-chunk slot, 0..511
      int row = s >> 2;                     // tile row 0..127
      int c4 = (s & 3) ^ ((row >> 1) & 3);  // XOR swizzle
      cp16(A + (size_t)(m0 + row) * 1024 + k0 + c4 * 8,
           Asm + (size_t)(p * 256 + w * 64) * 8);
      cp16(Bt + (size_t)(n0 + row) * 1024 + k0 + c4 * 8,
           Bsm + (size_t)(p * 256 + w * 64) * 8);
    }
    __syncthreads();  // drains vmcnt(0) then barrier

    short8 a[4], b[4];
#pragma unroll
    for (int i = 0; i < 4; ++i) {
      int row = wm + i * 16 + l16;
      int c4 = quad ^ ((row >> 1) & 3);
      a[i] = *(const short8*)(Asm + row * 32 + c4 * 8);
    }
#pragma unroll
    for (int j = 0; j < 4; ++j) {
      int row = wn + j * 16 + l16;
      int c4 = quad ^ ((row >> 1) & 3);
      b[j] = *(const short8*)(Bsm + row * 32 + c4 * 8);
    }
#pragma unroll
    for (int i = 0; i < 4; ++i)
#pragma unroll
      for (int j = 0; j < 4; ++j)
        acc[i][j] = mfma16(a[i], b[j], acc[i][j]);
  }
}

// ---------------------------------------------------------------- QKV GEMM
__global__ __launch_bounds__(256) void gemm_qkv_kernel(
    const u16* __restrict__ x, const u16* __restrict__ Wt,
    const float* __restrict__ bias,
    u16* __restrict__ qb, u16* __restrict__ kb, u16* __restrict__ vtb) {
  __shared__ __align__(16) u16 Asm[128 * 32];
  __shared__ __align__(16) u16 Bsm[128 * 32];
  f32x4 acc[4][4];
  const int m0 = blockIdx.y * 128;
  const int n0 = blockIdx.x * 128;
  gemm128_core(x, Wt, m0, n0, Asm, Bsm, acc);

  const int tid = threadIdx.x;
  const int w = tid >> 6, lane = tid & 63, quad = lane >> 4, l16 = lane & 15;
  const int wm = (w >> 1) * 64, wn = (w & 1) * 64;
#pragma unroll
  for (int j = 0; j < 4; ++j) {
    int col = n0 + wn + j * 16 + l16;
    float bv = bias[col];
    int which = col >> 10;     // 0=q 1=k 2=v
    int rem = col & 1023;
    int h = rem >> 6, d = rem & 63;
#pragma unroll
    for (int i = 0; i < 4; ++i) {
#pragma unroll
      for (int r = 0; r < 4; ++r) {
        int m = m0 + wm + i * 16 + quad * 4 + r;   // C/D: row=quad*4+r, col=l16
        int b_ = m >> 11, t = m & 2047;
        int bh = b_ * N_HEADS + h;
        u16 o = f2b(acc[i][j][r] + bv);
        if (which == 0)
          qb[((size_t)(bh * TSEQ + t) << 6) + d] = o;
        else if (which == 1)
          kb[((size_t)(bh * TSEQ + t) << 6) + d] = o;
        else  // V transposed: [bh][d][t] so flash PV B-frags read contiguous
          vtb[((size_t)((bh << 6) + d)) * TSEQ + t] = o;
      }
    }
  }
}

// ---------------------------------------------------------------- attention
// One block per (q-tile of 64 rows, bh). 4 waves, wave w owns q rows w*16..+15.
__global__ __launch_bounds__(256) void attn_kernel(const u16* __restrict__ qb,
                                                   const u16* __restrict__ kb,
                                                   const u16* __restrict__ vtb,
                                                   u16* __restrict__ ob) {
  const int qt = blockIdx.x;  // 0..31
  const int bh = blockIdx.y;  // 0..63
  __shared__ __align__(16) u16 Ksm[64 * 64];       // [t_k][d], swizzled chunks
  __shared__ __align__(16) u16 Vsm[64 * 64];       // [d][t_k], swizzled chunks
  __shared__ __align__(16) u16 Psm[4 * 16 * 72];   // per-wave P, stride 72 (pad)
  const int tid = threadIdx.x;
  const int w = tid >> 6, lane = tid & 63, quad = lane >> 4, l16 = lane & 15;

  // Q fragments, kept in registers for the whole kernel
  const u16* qrow = qb + ((size_t)(bh * TSEQ + qt * 64 + w * 16 + l16)) * 64;
  short8 qf0 = *(const short8*)(qrow + quad * 8);
  short8 qf1 = *(const short8*)(qrow + 32 + quad * 8);

  f32x4 o[4];
#pragma unroll
  for (int j = 0; j < 4; ++j) o[j] = (f32x4){0.f, 0.f, 0.f, 0.f};
  float mst[4], lst[4];
#pragma unroll
  for (int r = 0; r < 4; ++r) { mst[r] = -3e38f; lst[r] = 0.f; }
  const float cexp = 0.18033688011112042f;  // (1/sqrt(64)) * log2(e)

  const u16* kb_bh = kb + (size_t)bh * TSEQ * 64;
  const u16* vt_bh = vtb + (size_t)bh * 64 * TSEQ;
  u16* pw = Psm + w * 16 * 72;

  for (int kt = 0; kt <= qt; ++kt) {
    __syncthreads();
    const u16* kbase = kb_bh + (size_t)(kt * 64) * 64;   // contiguous 64x64 tile
    const u16* vbase = vt_bh + kt * 64;                  // rows stride TSEQ
#pragma unroll
    for (int p = 0; p < 2; ++p) {
      int s = p * 256 + tid;            // chunk slot 0..511
      int row = s >> 3;                 // 0..63
      int c8 = (s & 7) ^ (row & 7);     // XOR swizzle
      cp16(kbase + row * 64 + c8 * 8, Ksm + (size_t)(p * 256 + w * 64) * 8);
      cp16(vbase + (size_t)row * TSEQ + c8 * 8, Vsm + (size_t)(p * 256 + w * 64) * 8);
    }
    __syncthreads();

    // S = Q K^T for this wave's 16 rows x 64 k-cols
    f32x4 s[4];
#pragma unroll
    for (int j = 0; j < 4; ++j) {
      int row = j * 16 + l16;
      int ca = (quad) ^ (row & 7);
      int cb = (4 + quad) ^ (row & 7);
      short8 k0 = *(const short8*)(Ksm + row * 64 + ca * 8);
      short8 k1 = *(const short8*)(Ksm + row * 64 + cb * 8);
      s[j] = (f32x4){0.f, 0.f, 0.f, 0.f};
      s[j] = mfma16(qf0, k0, s[j]);
      s[j] = mfma16(qf1, k1, s[j]);
    }
    if (kt == qt) {  // diagonal tile: mask k > q
#pragma unroll
      for (int j = 0; j < 4; ++j) {
        int krow = j * 16 + l16;
#pragma unroll
        for (int r = 0; r < 4; ++r) {
          int qrow_l = w * 16 + quad * 4 + r;
          if (krow > qrow_l) s[j][r] = -1e30f;
        }
      }
    }

    // online softmax (row quad*4+r lives across the 16 lanes sharing `quad`)
    float pv[4][4];
#pragma unroll
    for (int r = 0; r < 4; ++r) {
      float mx = fmaxf(fmaxf(s[0][r], s[1][r]), fmaxf(s[2][r], s[3][r]));
      mx = fmaxf(mx, __shfl_xor(mx, 1));
      mx = fmaxf(mx, __shfl_xor(mx, 2));
      mx = fmaxf(mx, __shfl_xor(mx, 4));
      mx = fmaxf(mx, __shfl_xor(mx, 8));
      float mnew = fmaxf(mst[r], mx);
      float alpha = exp2f((mst[r] - mnew) * cexp);
      float rs = 0.f;
#pragma unroll
      for (int j = 0; j < 4; ++j) {
        float p_ = exp2f((s[j][r] - mnew) * cexp);
        pv[j][r] = p_;
        rs += p_;
      }
      rs += __shfl_xor(rs, 1);
      rs += __shfl_xor(rs, 2);
      rs += __shfl_xor(rs, 4);
      rs += __shfl_xor(rs, 8);
      lst[r] = lst[r] * alpha + rs;
      mst[r] = mnew;
#pragma unroll
      for (int j = 0; j < 4; ++j) o[j][r] *= alpha;
    }

    // P (C-layout) -> LDS (bf16) -> A-layout fragments (per-wave region)
#pragma unroll
    for (int j = 0; j < 4; ++j)
#pragma unroll
      for (int r = 0; r < 4; ++r)
        pw[(quad * 4 + r) * 72 + j * 16 + l16] = f2b(pv[j][r]);
    asm volatile("s_waitcnt lgkmcnt(0)" ::: "memory");

    short8 ap0 = *(const short8*)(pw + l16 * 72 + quad * 8);
    short8 ap1 = *(const short8*)(pw + l16 * 72 + 32 + quad * 8);
#pragma unroll
    for (int j = 0; j < 4; ++j) {
      int row = j * 16 + l16;  // d
      int ca = (quad) ^ (row & 7);
      int cb = (4 + quad) ^ (row & 7);
      short8 v0 = *(const short8*)(Vsm + row * 64 + ca * 8);
      short8 v1 = *(const short8*)(Vsm + row * 64 + cb * 8);
      o[j] = mfma16(ap0, v0, o[j]);
      o[j] = mfma16(ap1, v1, o[j]);
    }
  }

  // epilogue: O/l -> attn buffer in [b][t][h*64+d] layout (ready for out GEMM)
  const int b_ = bh >> 4, h = bh & 15;
#pragma unroll
  for (int j = 0; j < 4; ++j) {
#pragma unroll
    for (int r = 0; r < 4; ++r) {
      int t = qt * 64 + w * 16 + quad * 4 + r;
      int d = j * 16 + l16;
      ob[((size_t)(b_ * TSEQ + t)) * 1024 + h * 64 + d] = f2b(o[j][r] / lst[r]);
    }
  }
}

// ------------------------------------------------------- out GEMM (fp32 out)
__global__ __launch_bounds__(256) void gemm_out_kernel(
    const u16* __restrict__ attn, const u16* __restrict__ Wt,
    const float* __restrict__ bias, float* __restrict__ out) {
  __shared__ __align__(16) u16 Asm[128 * 32];
  __shared__ __align__(16) u16 Bsm[128 * 32];
  f32x4 acc[4][4];
  const int m0 = blockIdx.y * 128;
  const int n0 = blockIdx.x * 128;
  gemm128_core(attn, Wt, m0, n0, Asm, Bsm, acc);

  const int tid = threadIdx.x;
  const int w = tid >> 6, lane = tid & 63, quad = lane >> 4, l16 = lane & 15;
  const int wm = (w >> 1) * 64, wn = (w & 1) * 64;
#pragma unroll
  for (int j = 0; j < 4; ++j) {
    int col = n0 + wn + j * 16 + l16;
    float bv = bias[col];
#pragma unroll
    for (int i = 0; i < 4; ++i)
#pragma unroll
      for (int r = 0; r < 4; ++r) {
        int m = m0 + wm + i * 16 + quad * 4 + r;
        out[(size_t)m * 1024 + col] = acc[i][j][r] + bv;
      }
  }
}

// ---------------------------------------------------------------- launcher
extern "C" void kernel_launch(void* const* d_in, const int* in_sizes, int n_in,
                              void* d_out, int out_size, void* d_ws, size_t ws_size,
                              hipStream_t stream) {
  const float* x    = (const float*)d_in[0];   // [8192][1024] fp32
  const float* Wqkv = (const float*)d_in[1];   // [1024][3072] fp32
  const float* bqkv = (const float*)d_in[2];   // [3072] fp32
  const float* Wout = (const float*)d_in[3];   // [1024][1024] fp32
  const float* bout = (const float*)d_in[4];   // [1024] fp32
  float* out = (float*)d_out;                  // [8192][1024] fp32

  u16* ws = (u16*)d_ws;
  u16* xb     = ws;                                  // 8M   bf16 x
  u16* wqkv_t = xb + (size_t)MROWS * 1024;           // 3M   [3072][1024]
  u16* wout_t = wqkv_t + (size_t)N3 * 1024;          // 1M   [1024][1024]
  u16* qbuf   = wout_t + (size_t)1024 * 1024;        // 8M   [bh][t][d]
  u16* kbuf   = qbuf + (size_t)MROWS * 1024;         // 8M   [bh][t][d]
  u16* vtbuf  = kbuf + (size_t)MROWS * 1024;         // 8M   [bh][d][t]
  u16* obuf   = vtbuf + (size_t)MROWS * 1024;        // 8M   [b][t][c]
  (void)ws_size; (void)n_in; (void)in_sizes; (void)out_size;

  int n4 = MROWS * 1024 / 4;
  cvt_f32_bf16<<<(n4 + 255) / 256, 256, 0, stream>>>(x, xb, n4);
  transpose_cvt<<<dim3(N3 / 32, 1024 / 32), dim3(32, 8), 0, stream>>>(Wqkv, wqkv_t, 1024, N3);
  transpose_cvt<<<dim3(1024 / 32, 1024 / 32), dim3(32, 8), 0, stream>>>(Wout, wout_t, 1024, 1024);
  gemm_qkv_kernel<<<dim3(N3 / 128, MROWS / 128), 256, 0, stream>>>(xb, wqkv_t, bqkv, qbuf, kbuf, vtbuf);
  attn_kernel<<<dim3(TSEQ / 64, BATCH * N_HEADS), 256, 0, stream>>>(qbuf, kbuf, vtbuf, obuf);
  gemm_out_kernel<<<dim3(1024 / 128, MROWS / 128), 256, 0, stream>>>(obuf, wout_t, bout, out);
}